// Round 1
// baseline (116.809 us; speedup 1.0000x reference)
//
#include <hip/hip_runtime.h>
#include <math.h>

using short8  = __attribute__((ext_vector_type(8))) short;
using floatx4 = __attribute__((ext_vector_type(4))) float;

#define GLD16(gsrc, ldst) __builtin_amdgcn_global_load_lds( \
    (const __attribute__((address_space(1))) void*)(gsrc),  \
    (__attribute__((address_space(3))) void*)(ldst), 16, 0, 0)

__device__ __forceinline__ unsigned short f2bf(float x) {
  union { float f; unsigned u; } v; v.f = x;
  unsigned r = (v.u + 0x7FFFu + ((v.u >> 16) & 1u)) >> 16;
  return (unsigned short)r;
}

// ---------------- K1: Wh = h @ W  (f32 vector GEMM, 64x128 tile) ----------------
__global__ __launch_bounds__(256) void wh_gemm(
    const float* __restrict__ h, const float* __restrict__ W,
    float* __restrict__ Wh) {
  __shared__ __align__(16) float Al[16][64];    // [k][m]
  __shared__ __align__(16) float Bl[16][128];   // [k][n]
  const int m0 = blockIdx.x * 64;
  const int n0 = blockIdx.y * 128;
  const int t  = threadIdx.x;
  const int tx = t & 15, ty = t >> 4;
  float acc[4][8];
#pragma unroll
  for (int i = 0; i < 4; ++i)
#pragma unroll
    for (int j = 0; j < 8; ++j) acc[i][j] = 0.0f;

  for (int k0 = 0; k0 < 256; k0 += 16) {
    { // stage A (transpose to [k][m])
      int m = t & 63, kq = t >> 6;
      float4 v = *(const float4*)&h[(size_t)(m0 + m) * 256 + k0 + kq * 4];
      Al[kq * 4 + 0][m] = v.x; Al[kq * 4 + 1][m] = v.y;
      Al[kq * 4 + 2][m] = v.z; Al[kq * 4 + 3][m] = v.w;
    }
    { // stage B
      int n4 = t & 31, kr = t >> 5;
      *(float4*)&Bl[kr][n4 * 4]     = *(const float4*)&W[(size_t)(k0 + kr) * 256 + n0 + n4 * 4];
      *(float4*)&Bl[kr + 8][n4 * 4] = *(const float4*)&W[(size_t)(k0 + kr + 8) * 256 + n0 + n4 * 4];
    }
    __syncthreads();
#pragma unroll
    for (int k = 0; k < 16; ++k) {
      float4 av = *(const float4*)&Al[k][ty * 4];
      float4 b0 = *(const float4*)&Bl[k][tx * 4];
      float4 b1 = *(const float4*)&Bl[k][64 + tx * 4];
      float aa[4] = {av.x, av.y, av.z, av.w};
      float bb[8] = {b0.x, b0.y, b0.z, b0.w, b1.x, b1.y, b1.z, b1.w};
#pragma unroll
      for (int i = 0; i < 4; ++i)
#pragma unroll
        for (int j = 0; j < 8; ++j) acc[i][j] = fmaf(aa[i], bb[j], acc[i][j]);
    }
    __syncthreads();
  }
#pragma unroll
  for (int i = 0; i < 4; ++i) {
    size_t row = (size_t)(m0 + ty * 4 + i);
    float4 o0 = make_float4(acc[i][0], acc[i][1], acc[i][2], acc[i][3]);
    float4 o1 = make_float4(acc[i][4], acc[i][5], acc[i][6], acc[i][7]);
    *(float4*)&Wh[row * 256 + n0 + tx * 4]      = o0;
    *(float4*)&Wh[row * 256 + n0 + 64 + tx * 4] = o1;
  }
}

// ---------------- K2a: g[row] = Wh[row,:] . a2  (one wave per row) ----------------
__global__ __launch_bounds__(256) void g_rows(
    const float* __restrict__ Wh, const float* __restrict__ a,
    float* __restrict__ g) {
  int row = blockIdx.x * 4 + (threadIdx.x >> 6);
  int L = threadIdx.x & 63;
  float4 w  = *(const float4*)&Wh[(size_t)row * 256 + L * 4];
  float4 av = *(const float4*)&a[256 + L * 4];
  float d = w.x * av.x + w.y * av.y + w.z * av.z + w.w * av.w;
#pragma unroll
  for (int off = 32; off > 0; off >>= 1) d += __shfl_xor(d, off);
  if (L == 0) g[row] = d;
}

// ---------------- K2b: per-batch max of g ----------------
__global__ __launch_bounds__(256) void batch_max(
    const float* __restrict__ g, float* __restrict__ Mb) {
  __shared__ float red[4];
  int b = blockIdx.x, t = threadIdx.x;
  float m = -1e30f;
  for (int i = t; i < 2048; i += 256) m = fmaxf(m, g[(size_t)b * 2048 + i]);
#pragma unroll
  for (int off = 32; off > 0; off >>= 1) m = fmaxf(m, __shfl_xor(m, off));
  if ((t & 63) == 0) red[t >> 6] = m;
  __syncthreads();
  if (t == 0) Mb[b] = fmaxf(fmaxf(red[0], red[1]), fmaxf(red[2], red[3]));
}

// ---------------- K2c: Bt[b][c][j] = bf16(s_j * Wh[b,j,c]); col 256 = s_j; 257..287 = 0
__global__ __launch_bounds__(256) void build_bt(
    const float* __restrict__ Wh, const float* __restrict__ g,
    const float* __restrict__ Mb, unsigned short* __restrict__ Bt) {
  __shared__ __align__(16) unsigned short tile[288 * 64];  // [c][j]
  const int blk = blockIdx.x;
  const int b   = blk >> 5;
  const int j0  = (blk & 31) * 64;
  const int t   = threadIdx.x;
  const int j   = t & 63;
  const int q0  = t >> 6;
  const int row = b * 2048 + j0 + j;
  const float s = expf(g[row] - Mb[b]);
  for (int q = q0; q < 64; q += 4) {
    float4 wv = *(const float4*)&Wh[(size_t)row * 256 + q * 4];
    int c = q * 4;
    tile[(c + 0) * 64 + j] = f2bf(s * wv.x);
    tile[(c + 1) * 64 + j] = f2bf(s * wv.y);
    tile[(c + 2) * 64 + j] = f2bf(s * wv.z);
    tile[(c + 3) * 64 + j] = f2bf(s * wv.w);
  }
  if (q0 == 0) tile[256 * 64 + j] = f2bf(s);
  for (int z = t; z < 31 * 64; z += 256) tile[257 * 64 + z] = 0;
  __syncthreads();
#pragma unroll
  for (int p = 0; p < 9; ++p) {
    int id = t + 256 * p;          // 0..2303
    int c = id >> 3, off = id & 7;
    int4 v = *(const int4*)&tile[c * 64 + off * 8];
    *(int4*)((char*)Bt + (size_t)(b * 288 + c) * 4096 + j0 * 2 + off * 16) = v;
  }
}

// ---------------- K3: per batch:  [num|den] = adj @ Bt^T, epilogue div+elu -> out
// grid 256: b = bid&7 (one batch per XCD), rb = bid>>3. BM=64, BN=288, BK=32.
__global__ __launch_bounds__(256) void gat_main(
    const int* __restrict__ adj, const unsigned short* __restrict__ Bt,
    float* __restrict__ out) {
  __shared__ __align__(16) char lds[45056];  // A dbuf 2x4096 | B dbuf 2x18432
  const int bid = blockIdx.x;
  const int b   = bid & 7;
  const int rb  = bid >> 3;
  const int i0  = rb * 64;
  const int t   = threadIdx.x;
  const int w   = t >> 6, L = t & 63;
  const int wm  = w >> 1, wn = w & 1;
  const int* adjb = adj + ((size_t)b * 2048 + i0) * 2048;
  const char* Btb = (const char*)Bt + (size_t)b * 288 * 2048 * 2;

  floatx4 acc[2][9];
#pragma unroll
  for (int i = 0; i < 2; ++i)
#pragma unroll
    for (int n = 0; n < 9; ++n) acc[i][n] = (floatx4)0.0f;

  // A staging: thread -> row ar, k-chunk akq (8 ints -> 8 bf16 = one 16B chunk)
  const int ar  = t >> 2;
  const int akq = t & 3;
  const int* asrc = adjb + (size_t)ar * 2048 + akq * 8;
  const int awoff = ar * 64 + ((akq ^ ((ar >> 1) & 3)) << 4);   // XOR-swizzled slot

  // B staging: per-lane pre-swizzled global source (LDS dest stays linear)
  const char* bsrc = Btb + ((size_t)(L >> 2) * 4096) + (((L & 3) ^ ((L >> 3) & 3)) << 4);

  char* ldsA0 = lds;
  char* ldsA1 = lds + 4096;
  char* ldsB0 = lds + 8192;
  char* ldsB1 = lds + 8192 + 18432;

  // prologue: stage tile 0
  {
    int4 v0 = *(const int4*)(asrc + 0);
    int4 v1 = *(const int4*)(asrc + 4);
#pragma unroll
    for (int p = 0; p < 5; ++p) {
      int qq = w + p * 4;
      if (qq < 18) GLD16(bsrc + (size_t)qq * 65536, ldsB0 + qq * 1024);
    }
    unsigned p0 = ((unsigned)v0.x | ((unsigned)v0.y << 16)) * 0x3F80u;
    unsigned p1 = ((unsigned)v0.z | ((unsigned)v0.w << 16)) * 0x3F80u;
    unsigned p2 = ((unsigned)v1.x | ((unsigned)v1.y << 16)) * 0x3F80u;
    unsigned p3 = ((unsigned)v1.z | ((unsigned)v1.w << 16)) * 0x3F80u;
    *(uint4*)(ldsA0 + awoff) = make_uint4(p0, p1, p2, p3);
  }
  __syncthreads();

  const int kc = L >> 4;
  const int fr = L & 15;
  for (int kt = 0; kt < 64; ++kt) {
    char* lA  = (kt & 1) ? ldsA1 : ldsA0;
    char* lB  = (kt & 1) ? ldsB1 : ldsB0;
    char* lAn = (kt & 1) ? ldsA0 : ldsA1;
    char* lBn = (kt & 1) ? ldsB0 : ldsB1;
    int4 v0, v1;
    if (kt < 63) {
      int k0n = (kt + 1) * 32;
      v0 = *(const int4*)(asrc + k0n);       // A reg loads first (older in vmcnt)
      v1 = *(const int4*)(asrc + k0n + 4);
#pragma unroll
      for (int p = 0; p < 5; ++p) {
        int qq = w + p * 4;
        if (qq < 18) GLD16(bsrc + (size_t)qq * 65536 + (size_t)k0n * 2, lBn + qq * 1024);
      }
    }
    // compute current tile: per wave 2x9 fragments, k=32 in one MFMA step
    short8 af[2];
#pragma unroll
    for (int mf = 0; mf < 2; ++mf) {
      int r = wm * 32 + mf * 16 + fr;
      af[mf] = *(const short8*)(lA + r * 64 + ((kc ^ ((r >> 1) & 3)) << 4));
    }
#pragma unroll
    for (int nf = 0; nf < 9; ++nf) {
      int c = wn * 144 + nf * 16 + fr;
      short8 bfv = *(const short8*)(lB + c * 64 + ((kc ^ ((c >> 1) & 3)) << 4));
      acc[0][nf] = __builtin_amdgcn_mfma_f32_16x16x32_bf16(af[0], bfv, acc[0][nf], 0, 0, 0);
      acc[1][nf] = __builtin_amdgcn_mfma_f32_16x16x32_bf16(af[1], bfv, acc[1][nf], 0, 0, 0);
    }
    if (kt < 63) {
      unsigned p0 = ((unsigned)v0.x | ((unsigned)v0.y << 16)) * 0x3F80u;
      unsigned p1 = ((unsigned)v0.z | ((unsigned)v0.w << 16)) * 0x3F80u;
      unsigned p2 = ((unsigned)v1.x | ((unsigned)v1.y << 16)) * 0x3F80u;
      unsigned p3 = ((unsigned)v1.z | ((unsigned)v1.w << 16)) * 0x3F80u;
      *(uint4*)(lAn + awoff) = make_uint4(p0, p1, p2, p3);
    }
    __syncthreads();
  }

  // epilogue: den = column 256 (wn==1, nf==7, fr==0)
  float* denArr = (float*)lds;
  const int fq = L >> 4;
  if (wn == 1 && fr == 0) {
#pragma unroll
    for (int mf = 0; mf < 2; ++mf)
#pragma unroll
      for (int jj = 0; jj < 4; ++jj)
        denArr[wm * 32 + mf * 16 + fq * 4 + jj] = acc[mf][7][jj];
  }
  __syncthreads();
  float invd[2][4];
#pragma unroll
  for (int mf = 0; mf < 2; ++mf)
#pragma unroll
    for (int jj = 0; jj < 4; ++jj)
      invd[mf][jj] = 1.0f / denArr[wm * 32 + mf * 16 + fq * 4 + jj];
#pragma unroll
  for (int mf = 0; mf < 2; ++mf) {
#pragma unroll
    for (int nf = 0; nf < 9; ++nf) {
      int col = wn * 144 + nf * 16 + fr;
      if (col < 256) {
#pragma unroll
        for (int jj = 0; jj < 4; ++jj) {
          int r = wm * 32 + mf * 16 + fq * 4 + jj;
          float v = acc[mf][nf][jj] * invd[mf][jj];
          v = (v > 0.0f) ? v : expm1f(v);
          out[((size_t)b * 2048 + i0 + r) * 256 + col] = v;
        }
      }
    }
  }
}

extern "C" void kernel_launch(void* const* d_in, const int* in_sizes, int n_in,
                              void* d_out, int out_size, void* d_ws, size_t ws_size,
                              hipStream_t stream) {
  const float* h   = (const float*)d_in[0];
  const int*   adj = (const int*)d_in[1];
  const float* W   = (const float*)d_in[2];
  const float* a   = (const float*)d_in[3];
  float* out = (float*)d_out;

  char* ws = (char*)d_ws;
  if (ws_size < 26280192) return;  // need ~26.3 MB scratch
  float* Wh          = (float*)ws;                    // 16,777,216 B
  float* g           = (float*)(ws + 16777216);       //     65,536 B
  float* Mb          = (float*)(ws + 16842752);       //        256 B
  unsigned short* Bt = (unsigned short*)(ws + 16843008); // 9,437,184 B

  wh_gemm  <<<dim3(256, 2), 256, 0, stream>>>(h, W, Wh);
  g_rows   <<<4096,        256, 0, stream>>>(Wh, a, g);
  batch_max<<<8,           256, 0, stream>>>(g, Mb);
  build_bt <<<256,         256, 0, stream>>>(Wh, g, Mb, Bt);
  gat_main <<<256,         256, 0, stream>>>(adj, Bt, out);
}